// Round 1
// baseline (625.106 us; speedup 1.0000x reference)
//
#include <hip/hip_runtime.h>
#include <math.h>

#define NTOK   32768
#define DIM    512
#define NTYPES 26
#define PT     128
#define NCODES 3328
#define NSAMP  312
#define INV_TEMP (1.0f / 0.07f)

#define COMP(v,u) ((u)==0?(v).x:((u)==1?(v).y:((u)==2?(v).z:(v).w)))

// ---------------- init: zero counters + accumulators ----------------
__global__ void k_init(int* counts, float* accg) {
    int tid = threadIdx.x;
    if (tid < NTYPES) counts[tid] = 0;
    if (tid >= 32 && tid < 34) accg[tid - 32] = 0.0f;
}

// ---------------- per-code ||e||^2 and 1/||e|| ----------------
__global__ __launch_bounds__(256) void k_codes(const float* __restrict__ emb,
                                               float* __restrict__ sume,
                                               float* __restrict__ rinv) {
    int wv = threadIdx.x >> 6, lane = threadIdx.x & 63;
    int c = blockIdx.x * 4 + wv;
    const float4* row = (const float4*)(emb + (size_t)c * DIM);
    float4 v0 = row[lane * 2], v1 = row[lane * 2 + 1];
    float s = v0.x*v0.x + v0.y*v0.y + v0.z*v0.z + v0.w*v0.w
            + v1.x*v1.x + v1.y*v1.y + v1.z*v1.z + v1.w*v1.w;
    for (int m = 32; m; m >>= 1) s += __shfl_down(s, m);
    if (lane == 0) {
        sume[c] = s;
        rinv[c] = 1.0f / fmaxf(sqrtf(s), 1e-12f);
    }
}

// ---------------- normalize x -> xn (stored in d_out), rank per type ----------------
__global__ __launch_bounds__(256) void k_norm(const float* __restrict__ x,
                                              const int* __restrict__ Q,
                                              float* __restrict__ outbuf,
                                              int* __restrict__ counts,
                                              int* __restrict__ rank) {
    int wv = threadIdx.x >> 6, lane = threadIdx.x & 63;
    int t = blockIdx.x * 4 + wv;
    const float4* row = (const float4*)(x + (size_t)t * DIM);
    float4 v0 = row[lane * 2], v1 = row[lane * 2 + 1];
    float s = v0.x*v0.x + v0.y*v0.y + v0.z*v0.z + v0.w*v0.w
            + v1.x*v1.x + v1.y*v1.y + v1.z*v1.z + v1.w*v1.w;
    for (int m = 32; m; m >>= 1) s += __shfl_xor(s, m);
    float rn = 1.0f / fmaxf(sqrtf(s), 1e-12f);
    float4* orow = (float4*)(outbuf + (size_t)t * DIM);
    v0.x *= rn; v0.y *= rn; v0.z *= rn; v0.w *= rn;
    v1.x *= rn; v1.y *= rn; v1.z *= rn; v1.w *= rn;
    orow[lane * 2] = v0; orow[lane * 2 + 1] = v1;
    if (lane == 0) rank[t] = atomicAdd(&counts[Q[t]], 1);
}

// ---------------- exclusive scan of 26 counts ----------------
__global__ void k_scan(const int* __restrict__ counts, int* __restrict__ offs) {
    offs[0] = 0;
    for (int i = 0; i < NTYPES; i++) offs[i + 1] = offs[i] + counts[i];
}

// ---------------- scatter token ids into type-bucketed order ----------------
__global__ __launch_bounds__(256) void k_scatter(const int* __restrict__ Q,
                                                 const int* __restrict__ offs,
                                                 const int* __restrict__ rank,
                                                 int* __restrict__ order) {
    int t = blockIdx.x * 256 + threadIdx.x;
    order[offs[Q[t]] + rank[t]] = t;
}

// ---------------- main: per-type distance GEMM + argmin + epilogue ----------------
__global__ __launch_bounds__(256) void k_main(const float* __restrict__ emb,
                                              const int* __restrict__ order,
                                              const int* __restrict__ offs,
                                              const float* __restrict__ sume,
                                              const float* __restrict__ rinv,
                                              float* __restrict__ outbuf,
                                              float* __restrict__ idxout,
                                              float* __restrict__ accg) {
    int q = blockIdx.x;
    int tile = blockIdx.y;
    int base = offs[q];
    int cnt = offs[q + 1] - base;
    int tstart = tile * 64;
    if (tstart >= cnt) return;
    int nt = min(64, cnt - tstart);

    __shared__ float As[64][68];    // [token][k]  (row stride 68: 16B-aligned, odd/32 bank step)
    __shared__ float Bs[64][132];   // [k][code]
    __shared__ float sume_s[128];
    __shared__ float rinv_s[128];
    __shared__ int   toks[64];
    __shared__ float redv[64 * 16];
    __shared__ int   redi[64 * 16];
    __shared__ int   bestc[64];
    __shared__ float wsum[4];

    int tid = threadIdx.x;
    int tx = tid & 15;    // code group: codes tx*8 .. tx*8+7
    int ty = tid >> 4;    // token group: tokens ty*4 .. ty*4+3

    if (tid < 64) toks[tid] = (tid < nt) ? order[base + tstart + tid] : 0;
    if (tid < 128) {
        sume_s[tid] = sume[q * PT + tid];
        rinv_s[tid] = rinv[q * PT + tid];
    }

    float accv[4][8];
#pragma unroll
    for (int i = 0; i < 4; i++)
#pragma unroll
        for (int j = 0; j < 8; j++) accv[i][j] = 0.0f;

    const float* eslab = emb + (size_t)q * PT * DIM;

    for (int kc = 0; kc < 8; kc++) {
        int k0 = kc * 64;
        __syncthreads();   // toks ready (iter 0) / LDS free (iter>0)
        // load A tile: 64 tokens x 64 k, coalesced float4 reads
#pragma unroll
        for (int i = 0; i < 4; i++) {
            int id = tid + i * 256;
            int t = id >> 4, kv = id & 15;
            float4 v = make_float4(0.f, 0.f, 0.f, 0.f);
            if (t < nt) v = *(const float4*)(outbuf + (size_t)toks[t] * DIM + k0 + kv * 4);
            *(float4*)&As[t][kv * 4] = v;
        }
        // load B tile: 128 codes x 64 k, transpose to k-major in LDS
#pragma unroll
        for (int i = 0; i < 8; i++) {
            int id = tid + i * 256;
            int c = id >> 4, kv = id & 15;
            float4 v = *(const float4*)(eslab + (size_t)c * DIM + k0 + kv * 4);
            Bs[kv * 4 + 0][c] = v.x;
            Bs[kv * 4 + 1][c] = v.y;
            Bs[kv * 4 + 2][c] = v.z;
            Bs[kv * 4 + 3][c] = v.w;
        }
        __syncthreads();
        // compute: 4 tokens x 8 codes per thread
#pragma unroll
        for (int kk4 = 0; kk4 < 16; kk4++) {
            float4 a0 = *(const float4*)&As[ty * 4 + 0][kk4 * 4];
            float4 a1 = *(const float4*)&As[ty * 4 + 1][kk4 * 4];
            float4 a2 = *(const float4*)&As[ty * 4 + 2][kk4 * 4];
            float4 a3 = *(const float4*)&As[ty * 4 + 3][kk4 * 4];
#pragma unroll
            for (int u = 0; u < 4; u++) {
                int kk = kk4 * 4 + u;
                float4 b0 = *(const float4*)&Bs[kk][tx * 8];
                float4 b1 = *(const float4*)&Bs[kk][tx * 8 + 4];
                float b[8] = {b0.x, b0.y, b0.z, b0.w, b1.x, b1.y, b1.z, b1.w};
                float a_[4] = {COMP(a0, u), COMP(a1, u), COMP(a2, u), COMP(a3, u)};
#pragma unroll
                for (int i = 0; i < 4; i++)
#pragma unroll
                    for (int j = 0; j < 8; j++)
                        accv[i][j] = fmaf(a_[i], b[j], accv[i][j]);
            }
        }
    }

    // per-thread argmin over its 8 codes, per token
#pragma unroll
    for (int i = 0; i < 4; i++) {
        int t = ty * 4 + i;
        float bv = 1e30f; int bc = 0;
#pragma unroll
        for (int j = 0; j < 8; j++) {
            int c = tx * 8 + j;
            float d = fmaf(-2.0f, accv[i][j], sume_s[c]);
            if (d < bv) { bv = d; bc = c; }   // strict <: first (lowest) code wins ties
        }
        redv[t * 16 + tx] = bv;
        redi[t * 16 + tx] = bc;
    }
    __syncthreads();
    if (tid < 64) {
        float bv = redv[tid * 16]; int bc = redi[tid * 16];
        for (int x2 = 1; x2 < 16; x2++) {
            float v = redv[tid * 16 + x2];
            if (v < bv) { bv = v; bc = redi[tid * 16 + x2]; }
        }
        bestc[tid] = bc;
        if (tid < nt) idxout[toks[tid]] = (float)(q * PT + bc);
    }
    __syncthreads();

    // epilogue: out = xn + (quantized - xn) in place; accumulate loss
    float lsum = 0.0f;
    for (int t = 0; t < nt; t++) {
        int c = bestc[t];
        float rv = rinv_s[c];
        const float* erow = eslab + (size_t)c * DIM;
        float* orow = outbuf + (size_t)toks[t] * DIM;
#pragma unroll
        for (int jj = 0; jj < 2; jj++) {
            int d = tid + jj * 256;
            float xnv = orow[d];
            float qv = erow[d] * rv;
            float diff = qv - xnv;
            orow[d] = xnv + diff;
            lsum += diff * diff;
        }
    }
    int lane = tid & 63, wv = tid >> 6;
    for (int m = 32; m; m >>= 1) lsum += __shfl_down(lsum, m);
    if (lane == 0) wsum[wv] = lsum;
    __syncthreads();
    if (tid == 0) atomicAdd(&accg[0], wsum[0] + wsum[1] + wsum[2] + wsum[3]);
}

// ---------------- uniform loss: one block per sampled row ----------------
__global__ __launch_bounds__(256) void k_uloss(const float* __restrict__ emb,
                                               const int* __restrict__ samp,
                                               const float* __restrict__ rinv,
                                               float* __restrict__ accg) {
    __shared__ float sei[DIM];
    __shared__ float redS[4], redP[4];
    int i = blockIdx.x;
    int tid = threadIdx.x;
    int ci = samp[i];
    float rvi = rinv[ci];
    sei[tid]       = emb[(size_t)ci * DIM + tid] * rvi;
    sei[tid + 256] = emb[(size_t)ci * DIM + tid + 256] * rvi;
    __syncthreads();
    int labi = ci >> 7;
    float sumE = 0.0f, posE = 0.0f;
    for (int jj = 0; jj < 2; jj++) {
        int j = tid + jj * 256;
        if (j < NSAMP && j != i) {
            int cj = samp[j];
            float rvj = rinv[cj];
            const float4* ej = (const float4*)(emb + (size_t)cj * DIM);
            float dot = 0.0f;
#pragma unroll 4
            for (int d4 = 0; d4 < DIM / 4; d4++) {
                float4 e = ej[d4];
                float4 s = *(const float4*)&sei[d4 * 4];
                dot += e.x * s.x + e.y * s.y + e.z * s.z + e.w * s.w;
            }
            float sim = dot * rvj;
            float ex = expf(sim * INV_TEMP);
            sumE += ex;
            if ((cj >> 7) == labi) posE += ex;
        }
    }
    int lane = tid & 63, wv = tid >> 6;
    for (int m = 32; m; m >>= 1) {
        sumE += __shfl_down(sumE, m);
        posE += __shfl_down(posE, m);
    }
    if (lane == 0) { redS[wv] = sumE; redP[wv] = posE; }
    __syncthreads();
    if (tid == 0) {
        float S = redS[0] + redS[1] + redS[2] + redS[3];
        float P = redP[0] + redP[1] + redP[2] + redP[3];
        atomicAdd(&accg[1], logf(S) - logf(P));
    }
}

// ---------------- finalize scalars ----------------
__global__ void k_final(const float* __restrict__ accg, float* __restrict__ lossp) {
    lossp[0] = 1.25f * accg[0] / (float)((size_t)NTOK * DIM);  // q_latent + 0.25*e_latent
    lossp[1] = accg[1] / (float)NSAMP;
}

extern "C" void kernel_launch(void* const* d_in, const int* in_sizes, int n_in,
                              void* d_out, int out_size, void* d_ws, size_t ws_size,
                              hipStream_t stream) {
    const float* x   = (const float*)d_in[0];
    const float* emb = (const float*)d_in[1];
    const int* Q     = (const int*)d_in[2];
    const int* samp  = (const int*)d_in[3];

    float* out    = (float*)d_out;                       // [NTOK*DIM] xn then final out
    float* lossp  = out + (size_t)NTOK * DIM;            // loss, uloss
    float* idxout = out + (size_t)NTOK * DIM + 2;        // [NTOK] idx as float

    float* sume  = (float*)d_ws;                         // NCODES
    float* rinv  = sume + NCODES;                        // NCODES
    int* counts  = (int*)(rinv + NCODES);                // NTYPES
    int* offs    = counts + NTYPES;                      // NTYPES+1
    int* rank    = offs + NTYPES + 1;                    // NTOK
    int* order   = rank + NTOK;                          // NTOK
    float* accg  = (float*)(order + NTOK);               // [2]: loss sumsq, uloss sum

    k_init<<<1, 64, 0, stream>>>(counts, accg);
    k_codes<<<NCODES / 4, 256, 0, stream>>>(emb, sume, rinv);
    k_norm<<<NTOK / 4, 256, 0, stream>>>(x, Q, out, counts, rank);
    k_scan<<<1, 1, 0, stream>>>(counts, offs);
    k_scatter<<<NTOK / 256, 256, 0, stream>>>(Q, offs, rank, order);
    dim3 gmain(NTYPES, 32);
    k_main<<<gmain, 256, 0, stream>>>(emb, order, offs, sume, rinv, out, idxout, accg);
    k_uloss<<<NSAMP, 256, 0, stream>>>(emb, samp, rinv, accg);
    k_final<<<1, 1, 0, stream>>>(accg, lossp);
}

// Round 2
// 243.518 us; speedup vs baseline: 2.5670x; 2.5670x over previous
//
#include <hip/hip_runtime.h>
#include <math.h>

#define NTOK   32768
#define DIM    512
#define NTYPES 26
#define PT     128
#define NCODES 3328
#define NSAMP  312
#define INV_TEMP (1.0f / 0.07f)
#define MAXTILES 24   // covers per-type counts up to 1536 (mean 1260, sd ~35)

typedef __attribute__((ext_vector_type(8))) short short8;
typedef __attribute__((ext_vector_type(4))) float floatx4;

// split f into bf16 hi + bf16 lo (RNE both), f ~= hi + lo to ~2^-17 rel
__device__ __forceinline__ void f2bf2(float f, unsigned short& h, unsigned short& l) {
    unsigned u = __float_as_uint(f);
    unsigned hb = (u + 0x7fffu + ((u >> 16) & 1u)) >> 16;
    h = (unsigned short)hb;
    float hf = __uint_as_float(hb << 16);
    float r = f - hf;
    unsigned u2 = __float_as_uint(r);
    l = (unsigned short)((u2 + 0x7fffu + ((u2 >> 16) & 1u)) >> 16);
}

// ---------------- per-code ||e||^2, 1/||e||; block 0 zero-inits globals ----------------
__global__ __launch_bounds__(256) void k_codes(const float* __restrict__ emb,
                                               float* __restrict__ sume,
                                               float* __restrict__ rinv,
                                               int* __restrict__ counts,
                                               float* __restrict__ accg) {
    int tid = threadIdx.x;
    if (blockIdx.x == 0) {
        if (tid < NTYPES) counts[tid] = 0;
        if (tid == 32) accg[0] = 0.0f;
        if (tid == 33) accg[1] = 0.0f;
    }
    int wv = tid >> 6, lane = tid & 63;
    int c = blockIdx.x * 4 + wv;
    const float4* row = (const float4*)(emb + (size_t)c * DIM);
    float4 v0 = row[lane * 2], v1 = row[lane * 2 + 1];
    float s = v0.x*v0.x + v0.y*v0.y + v0.z*v0.z + v0.w*v0.w
            + v1.x*v1.x + v1.y*v1.y + v1.z*v1.z + v1.w*v1.w;
    for (int m = 32; m; m >>= 1) s += __shfl_xor(s, m);
    if (lane == 0) {
        sume[c] = s;
        rinv[c] = 1.0f / fmaxf(sqrtf(s), 1e-12f);
    }
}

// ---------------- per-token 1/||x|| (no xn materialization) ----------------
__global__ __launch_bounds__(256) void k_rnorm(const float* __restrict__ x,
                                               float* __restrict__ rnorm) {
    int wv = threadIdx.x >> 6, lane = threadIdx.x & 63;
    int t = blockIdx.x * 4 + wv;
    const float4* row = (const float4*)(x + (size_t)t * DIM);
    float4 v0 = row[lane * 2], v1 = row[lane * 2 + 1];
    float s = v0.x*v0.x + v0.y*v0.y + v0.z*v0.z + v0.w*v0.w
            + v1.x*v1.x + v1.y*v1.y + v1.z*v1.z + v1.w*v1.w;
    for (int m = 32; m; m >>= 1) s += __shfl_xor(s, m);
    if (lane == 0) rnorm[t] = 1.0f / fmaxf(sqrtf(s), 1e-12f);
}

// ---------------- two-level histogram: rank within type, low-contention ----------------
__global__ __launch_bounds__(256) void k_hist(const int* __restrict__ Q,
                                              int* __restrict__ counts,
                                              int* __restrict__ rank) {
    __shared__ int lbin[NTYPES];
    __shared__ int lbase[NTYPES];
    int tid = threadIdx.x;
    if (tid < NTYPES) lbin[tid] = 0;
    __syncthreads();
    int t = blockIdx.x * 256 + tid;
    int qt = Q[t];
    int lr = atomicAdd(&lbin[qt], 1);
    __syncthreads();
    if (tid < NTYPES) lbase[tid] = atomicAdd(&counts[tid], lbin[tid]);
    __syncthreads();
    rank[t] = lbase[qt] + lr;
}

// ---------------- exclusive scan of 26 counts ----------------
__global__ void k_scan(const int* __restrict__ counts, int* __restrict__ offs) {
    __shared__ int c[NTYPES];
    int tid = threadIdx.x;
    if (tid < NTYPES) c[tid] = counts[tid];
    __syncthreads();
    if (tid == 0) {
        int a = 0;
        offs[0] = 0;
        for (int i = 0; i < NTYPES; i++) { a += c[i]; offs[i + 1] = a; }
    }
}

// ---------------- scatter token ids into type-bucketed order ----------------
__global__ __launch_bounds__(256) void k_scatter(const int* __restrict__ Q,
                                                 const int* __restrict__ offs,
                                                 const int* __restrict__ rank,
                                                 int* __restrict__ order) {
    int t = blockIdx.x * 256 + threadIdx.x;
    order[offs[Q[t]] + rank[t]] = t;
}

// ---------------- main: bf16x3 MFMA distance GEMM + argmin + fused epilogue ----------------
// block = 256 thr (4 waves). Tile: 64 tokens x 128 codes, K staged 64 at a time.
// wave (wm,wn): wm=w&1 -> 32-token half, wn=w>>1 -> 64-code half. Per wave 2x4 16x16 tiles.
__global__ __launch_bounds__(256) void k_main(const float* __restrict__ x,
                                              const float* __restrict__ emb,
                                              const int* __restrict__ order,
                                              const int* __restrict__ offs,
                                              const float* __restrict__ sume,
                                              const float* __restrict__ rinv,
                                              const float* __restrict__ rnorm,
                                              float* __restrict__ outbuf,
                                              float* __restrict__ idxout,
                                              float* __restrict__ accg) {
    int q = blockIdx.x;
    int tile = blockIdx.y;
    int base = offs[q];
    int cnt = offs[q + 1] - base;
    int tstart = tile * 64;
    if (tstart >= cnt) return;
    int nt = min(64, cnt - tstart);

    __shared__ unsigned short Ah[64][72];   // row stride 144B = 16B-aligned, 2-way-max banks
    __shared__ unsigned short Al[64][72];
    __shared__ unsigned short Bh[128][72];
    __shared__ unsigned short Bl[128][72];
    __shared__ int   toks_s[64];
    __shared__ float rn_s[64];
    __shared__ float sume_s[128];
    __shared__ float rinv_s[128];
    __shared__ float redv[64][2];
    __shared__ int   redi[64][2];
    __shared__ int   bestc[64];
    __shared__ float wsum[4];

    int tid = threadIdx.x;
    int lane = tid & 63;
    int wv = tid >> 6;
    int wm = wv & 1, wn = wv >> 1;
    int lc = lane & 15;
    int q4 = lane >> 4;

    if (tid < 64) {
        int t = order[base + tstart + min(tid, nt - 1)];  // pad rows duplicate last valid
        toks_s[tid] = t;
        rn_s[tid] = rnorm[t];
    }
    if (tid < 128) {
        sume_s[tid] = sume[q * PT + tid];
        rinv_s[tid] = rinv[q * PT + tid];
    }

    floatx4 acc[2][4];
#pragma unroll
    for (int mi = 0; mi < 2; mi++)
#pragma unroll
        for (int ni = 0; ni < 4; ni++)
            acc[mi][ni] = (floatx4){0.f, 0.f, 0.f, 0.f};

    const float* eslab = emb + (size_t)q * PT * DIM;

    for (int kc = 0; kc < 8; kc++) {
        int k0 = kc * 64;
        __syncthreads();  // toks ready (iter 0) / LDS free (iter>0)
        // A: 64 tokens x 64 k fp32 -> bf16 hi/lo
#pragma unroll
        for (int i = 0; i < 4; i++) {
            int id = tid + i * 256;
            int r = id >> 4, sg = id & 15;
            float4 v = *(const float4*)(x + (size_t)toks_s[r] * DIM + k0 + sg * 4);
            ushort4 h, l;
            f2bf2(v.x, h.x, l.x); f2bf2(v.y, h.y, l.y);
            f2bf2(v.z, h.z, l.z); f2bf2(v.w, h.w, l.w);
            *(ushort4*)&Ah[r][sg * 4] = h;
            *(ushort4*)&Al[r][sg * 4] = l;
        }
        // B: 128 codes x 64 k fp32 -> bf16 hi/lo
#pragma unroll
        for (int i = 0; i < 8; i++) {
            int id = tid + i * 256;
            int r = id >> 4, sg = id & 15;
            float4 v = *(const float4*)(eslab + (size_t)r * DIM + k0 + sg * 4);
            ushort4 h, l;
            f2bf2(v.x, h.x, l.x); f2bf2(v.y, h.y, l.y);
            f2bf2(v.z, h.z, l.z); f2bf2(v.w, h.w, l.w);
            *(ushort4*)&Bh[r][sg * 4] = h;
            *(ushort4*)&Bl[r][sg * 4] = l;
        }
        __syncthreads();
#pragma unroll
        for (int ks2 = 0; ks2 < 2; ks2++) {
            int ko = ks2 * 32 + q4 * 8;
            short8 ahf[2], alf[2], bhf[4], blf[4];
#pragma unroll
            for (int mi = 0; mi < 2; mi++) {
                int m = wm * 32 + mi * 16 + lc;
                ahf[mi] = *(const short8*)&Ah[m][ko];
                alf[mi] = *(const short8*)&Al[m][ko];
            }
#pragma unroll
            for (int ni = 0; ni < 4; ni++) {
                int n = wn * 64 + ni * 16 + lc;
                bhf[ni] = *(const short8*)&Bh[n][ko];
                blf[ni] = *(const short8*)&Bl[n][ko];
            }
#pragma unroll
            for (int mi = 0; mi < 2; mi++)
#pragma unroll
                for (int ni = 0; ni < 4; ni++) {
                    acc[mi][ni] = __builtin_amdgcn_mfma_f32_16x16x32_bf16(ahf[mi], bhf[ni], acc[mi][ni], 0, 0, 0);
                    acc[mi][ni] = __builtin_amdgcn_mfma_f32_16x16x32_bf16(ahf[mi], blf[ni], acc[mi][ni], 0, 0, 0);
                    acc[mi][ni] = __builtin_amdgcn_mfma_f32_16x16x32_bf16(alf[mi], bhf[ni], acc[mi][ni], 0, 0, 0);
                }
        }
    }

    // argmin: C/D layout col=lane&15, row=(lane>>4)*4+reg
#pragma unroll
    for (int mi = 0; mi < 2; mi++) {
#pragma unroll
        for (int r = 0; r < 4; r++) {
            int m = wm * 32 + mi * 16 + q4 * 4 + r;
            float rn2 = -2.0f * rn_s[m];
            float bv = 1e30f; int bc = 0;
#pragma unroll
            for (int ni = 0; ni < 4; ni++) {
                int n = wn * 64 + ni * 16 + lc;
                float d = fmaf(rn2, acc[mi][ni][r], sume_s[n]);
                if (d < bv) { bv = d; bc = n; }   // n ascending: strict < keeps lowest
            }
#pragma unroll
            for (int mk = 1; mk <= 8; mk <<= 1) {  // butterfly over 16-lane row group
                float ov = __shfl_xor(bv, mk);
                int oc = __shfl_xor(bc, mk);
                if (ov < bv || (ov == bv && oc < bc)) { bv = ov; bc = oc; }
            }
            if (lc == 0) { redv[m][wn] = bv; redi[m][wn] = bc; }
        }
    }
    __syncthreads();
    if (tid < 64) {
        float v0 = redv[tid][0], v1 = redv[tid][1];
        int c = (v1 < v0) ? redi[tid][1] : redi[tid][0];  // tie -> lower cols (wn=0)
        bestc[tid] = c;
        if (tid < nt) idxout[toks_s[tid]] = (float)(q * PT + c);
    }
    __syncthreads();

    // epilogue: wave-parallel over tokens; out = xn + (quantized - xn); loss sum
    float lsum = 0.0f;
    for (int t = wv; t < nt; t += 4) {
        int c = bestc[t];
        int gt = toks_s[t];
        float rv = rinv_s[c];
        float rn = rn_s[t];
        const float4* xr = (const float4*)(x + (size_t)gt * DIM);
        const float4* er = (const float4*)(emb + (size_t)(q * PT + c) * DIM);
        float4* orow = (float4*)(outbuf + (size_t)gt * DIM);
#pragma unroll
        for (int s2 = 0; s2 < 2; s2++) {
            float4 xv = xr[lane * 2 + s2];
            float4 ev = er[lane * 2 + s2];
            float4 o;
            float xn, dx;
            xn = xv.x * rn; dx = ev.x * rv - xn; o.x = xn + dx; lsum += dx * dx;
            xn = xv.y * rn; dx = ev.y * rv - xn; o.y = xn + dx; lsum += dx * dx;
            xn = xv.z * rn; dx = ev.z * rv - xn; o.z = xn + dx; lsum += dx * dx;
            xn = xv.w * rn; dx = ev.w * rv - xn; o.w = xn + dx; lsum += dx * dx;
            orow[lane * 2 + s2] = o;
        }
    }
    for (int mk = 32; mk; mk >>= 1) lsum += __shfl_xor(lsum, mk);
    if (lane == 0) wsum[wv] = lsum;
    __syncthreads();
    if (tid == 0) atomicAdd(&accg[0], wsum[0] + wsum[1] + wsum[2] + wsum[3]);
}

// ---------------- uniform loss: block per row i, wave-per-j coalesced dots ----------------
__global__ __launch_bounds__(256) void k_uloss(const float* __restrict__ emb,
                                               const int* __restrict__ samp,
                                               const float* __restrict__ rinv,
                                               float* __restrict__ accg) {
    __shared__ float rs[4], rp[4];
    int i = blockIdx.x;
    int tid = threadIdx.x;
    int lane = tid & 63, wv = tid >> 6;
    int ci = samp[i];
    float rvi = rinv[ci];
    int labi = ci >> 7;
    const float4* ri = (const float4*)(emb + (size_t)ci * DIM);
    float4 e0 = ri[lane * 2], e1 = ri[lane * 2 + 1];   // row i stays in registers
    float sE = 0.0f, pE = 0.0f;
    for (int j = wv; j < NSAMP; j += 4) {
        if (j == i) continue;                           // wave-uniform
        int cj = samp[j];
        const float4* rj = (const float4*)(emb + (size_t)cj * DIM);
        float4 f0 = rj[lane * 2], f1 = rj[lane * 2 + 1];
        float d = e0.x*f0.x + e0.y*f0.y + e0.z*f0.z + e0.w*f0.w
                + e1.x*f1.x + e1.y*f1.y + e1.z*f1.z + e1.w*f1.w;
        for (int mk = 32; mk; mk >>= 1) d += __shfl_xor(d, mk);
        float ex = expf(d * rvi * rinv[cj] * INV_TEMP);
        sE += ex;
        if ((cj >> 7) == labi) pE += ex;
    }
    if (lane == 0) { rs[wv] = sE; rp[wv] = pE; }
    __syncthreads();
    if (tid == 0) {
        float S = rs[0] + rs[1] + rs[2] + rs[3];
        float P = rp[0] + rp[1] + rp[2] + rp[3];
        atomicAdd(&accg[1], logf(S) - logf(P));
    }
}

// ---------------- finalize scalars ----------------
__global__ void k_final(const float* __restrict__ accg, float* __restrict__ lossp) {
    lossp[0] = 1.25f * accg[0] / (float)((size_t)NTOK * DIM);  // q_latent + 0.25*e_latent
    lossp[1] = accg[1] / (float)NSAMP;
}

extern "C" void kernel_launch(void* const* d_in, const int* in_sizes, int n_in,
                              void* d_out, int out_size, void* d_ws, size_t ws_size,
                              hipStream_t stream) {
    const float* x   = (const float*)d_in[0];
    const float* emb = (const float*)d_in[1];
    const int* Q     = (const int*)d_in[2];
    const int* samp  = (const int*)d_in[3];

    float* out    = (float*)d_out;                       // [NTOK*DIM]
    float* lossp  = out + (size_t)NTOK * DIM;            // loss, uloss
    float* idxout = out + (size_t)NTOK * DIM + 2;        // [NTOK] idx as float

    float* sume  = (float*)d_ws;                         // NCODES
    float* rinv  = sume + NCODES;                        // NCODES
    float* rnorm = rinv + NCODES;                        // NTOK
    int* counts  = (int*)(rnorm + NTOK);                 // NTYPES
    int* offs    = counts + NTYPES;                      // NTYPES+1
    int* rank    = offs + NTYPES + 1;                    // NTOK
    int* order   = rank + NTOK;                          // NTOK
    float* accg  = (float*)(order + NTOK);               // [2]

    k_codes<<<NCODES / 4, 256, 0, stream>>>(emb, sume, rinv, counts, accg);
    k_rnorm<<<NTOK / 4, 256, 0, stream>>>(x, rnorm);
    k_hist<<<NTOK / 256, 256, 0, stream>>>(Q, counts, rank);
    k_scan<<<1, 64, 0, stream>>>(counts, offs);
    k_scatter<<<NTOK / 256, 256, 0, stream>>>(Q, offs, rank, order);
    dim3 gmain(NTYPES, MAXTILES);
    k_main<<<gmain, 256, 0, stream>>>(x, emb, order, offs, sume, rinv, rnorm, out, idxout, accg);
    k_uloss<<<NSAMP, 256, 0, stream>>>(emb, samp, rinv, accg);
    k_final<<<1, 1, 0, stream>>>(accg, lossp);
}

// Round 3
// 215.015 us; speedup vs baseline: 2.9073x; 1.1326x over previous
//
#include <hip/hip_runtime.h>
#include <math.h>

#define NTOK   32768
#define DIM    512
#define NTYPES 26
#define PT     128
#define NCODES 3328
#define NSAMP  312
#define INV_TEMP (1.0f / 0.07f)
#define MAXTILES 24

typedef __attribute__((ext_vector_type(8))) short short8;
typedef __attribute__((ext_vector_type(4))) float floatx4;

// split f into bf16 hi + bf16 lo (RNE both), f ~= hi + lo to ~2^-17 rel
__device__ __forceinline__ void f2bf2(float f, unsigned short& h, unsigned short& l) {
    unsigned u = __float_as_uint(f);
    unsigned hb = (u + 0x7fffu + ((u >> 16) & 1u)) >> 16;
    h = (unsigned short)hb;
    float hf = __uint_as_float(hb << 16);
    float r = f - hf;
    unsigned u2 = __float_as_uint(r);
    l = (unsigned short)((u2 + 0x7fffu + ((u2 >> 16) & 1u)) >> 16);
}

// ---------------- emb precompute: bf16 hi/lo planes + sume + rinv; zero-init globals ----------------
__global__ __launch_bounds__(256) void k_emb(const float* __restrict__ emb,
                                             unsigned short* __restrict__ Bhg,
                                             unsigned short* __restrict__ Blg,
                                             float* __restrict__ sume,
                                             float* __restrict__ rinv,
                                             int* __restrict__ counts,
                                             float* __restrict__ accg) {
    int tid = threadIdx.x;
    if (blockIdx.x == 0) {
        if (tid < NTYPES) counts[tid] = 0;
        if (tid == 32) accg[0] = 0.0f;
        if (tid == 33) accg[1] = 0.0f;
    }
    int wv = tid >> 6, lane = tid & 63;
    int c = blockIdx.x * 4 + wv;
    const float4* row = (const float4*)(emb + (size_t)c * DIM);
    float4 v0 = row[lane * 2], v1 = row[lane * 2 + 1];
    float s = v0.x*v0.x + v0.y*v0.y + v0.z*v0.z + v0.w*v0.w
            + v1.x*v1.x + v1.y*v1.y + v1.z*v1.z + v1.w*v1.w;
    for (int m = 32; m; m >>= 1) s += __shfl_xor(s, m);
    if (lane == 0) {
        sume[c] = s;
        rinv[c] = 1.0f / fmaxf(sqrtf(s), 1e-12f);
    }
    union { short8 v; unsigned short u[8]; } hh, ll;
    f2bf2(v0.x, hh.u[0], ll.u[0]); f2bf2(v0.y, hh.u[1], ll.u[1]);
    f2bf2(v0.z, hh.u[2], ll.u[2]); f2bf2(v0.w, hh.u[3], ll.u[3]);
    f2bf2(v1.x, hh.u[4], ll.u[4]); f2bf2(v1.y, hh.u[5], ll.u[5]);
    f2bf2(v1.z, hh.u[6], ll.u[6]); f2bf2(v1.w, hh.u[7], ll.u[7]);
    *(short8*)(Bhg + (size_t)c * DIM + lane * 8) = hh.v;
    *(short8*)(Blg + (size_t)c * DIM + lane * 8) = ll.v;
}

// ---------------- two-level histogram: rank within type ----------------
__global__ __launch_bounds__(256) void k_hist(const int* __restrict__ Q,
                                              int* __restrict__ counts,
                                              int* __restrict__ rank) {
    __shared__ int lbin[NTYPES];
    __shared__ int lbase[NTYPES];
    int tid = threadIdx.x;
    if (tid < NTYPES) lbin[tid] = 0;
    __syncthreads();
    int t = blockIdx.x * 256 + tid;
    int qt = Q[t];
    int lr = atomicAdd(&lbin[qt], 1);
    __syncthreads();
    if (tid < NTYPES) lbase[tid] = atomicAdd(&counts[tid], lbin[tid]);
    __syncthreads();
    rank[t] = lbase[qt] + lr;
}

// ---------------- scatter (with in-block scan); block 0 publishes offs ----------------
__global__ __launch_bounds__(256) void k_scatter(const int* __restrict__ Q,
                                                 const int* __restrict__ counts,
                                                 const int* __restrict__ rank,
                                                 int* __restrict__ order,
                                                 int* __restrict__ offsg) {
    __shared__ int offs[NTYPES];
    int tid = threadIdx.x;
    if (tid == 0) {
        int a = 0;
        for (int i = 0; i < NTYPES; i++) {
            offs[i] = a;
            if (blockIdx.x == 0) offsg[i] = a;
            a += counts[i];
        }
        if (blockIdx.x == 0) offsg[NTYPES] = a;
    }
    __syncthreads();
    int t = blockIdx.x * 256 + tid;
    order[offs[Q[t]] + rank[t]] = t;
}

// ---------------- main: fused rnorm + bf16x3 MFMA distance GEMM + argmin + epilogue ----------------
// block = 256 thr (4 waves). Tile: 64 tokens x 128 codes, K staged 64 at a time.
// LDS ~54 KB -> 3 blocks/CU. B tiles XOR-swizzled (16B granules) to stay unpadded+conflict-free.
__global__ __launch_bounds__(256, 3) void k_main(const float* __restrict__ x,
                                                 const float* __restrict__ emb,
                                                 const unsigned short* __restrict__ Bhg,
                                                 const unsigned short* __restrict__ Blg,
                                                 const int* __restrict__ order,
                                                 const int* __restrict__ offsg,
                                                 const float* __restrict__ sume,
                                                 const float* __restrict__ rinv,
                                                 float* __restrict__ outbuf,
                                                 float* __restrict__ idxout,
                                                 float* __restrict__ accg) {
    int q = blockIdx.x;
    int tile = blockIdx.y;
    int base = offsg[q];
    int cnt = offsg[q + 1] - base;
    int tstart = tile * 64;
    if (tstart >= cnt) return;
    int nt = min(64, cnt - tstart);

    __shared__ unsigned short Ah[64][72];      // padded: 2-way-max banks on r/w
    __shared__ unsigned short Al[64][72];
    __shared__ unsigned short Bh[128 * 64];    // XOR-swizzled, unpadded
    __shared__ unsigned short Bl[128 * 64];
    __shared__ int   toks_s[64];
    __shared__ float rn_s[64];
    __shared__ float sume_s[128];
    __shared__ float rinv_s[128];
    __shared__ float redv[64][2];
    __shared__ int   redi[64][2];
    __shared__ int   bestc[64];

    int tid = threadIdx.x;
    int lane = tid & 63;
    int wv = tid >> 6;
    int wm = wv & 1, wn = wv >> 1;
    int lc = lane & 15;
    int q4 = lane >> 4;

    if (tid < 64) toks_s[tid] = order[base + tstart + min(tid, nt - 1)];  // pad dups last
    if (tid < 128) {
        sume_s[tid] = sume[q * PT + tid];
        rinv_s[tid] = rinv[q * PT + tid];
    }

    floatx4 acc[2][4];
#pragma unroll
    for (int mi = 0; mi < 2; mi++)
#pragma unroll
        for (int ni = 0; ni < 4; ni++)
            acc[mi][ni] = (floatx4){0.f, 0.f, 0.f, 0.f};
    float ps[4] = {0.f, 0.f, 0.f, 0.f};   // per-thread sumsq partials (rows tid>>4 + 16i)

    const unsigned short* bh_slab = Bhg + (size_t)q * PT * DIM;
    const unsigned short* bl_slab = Blg + (size_t)q * PT * DIM;

    for (int kc = 0; kc < 8; kc++) {
        int k0 = kc * 64;
        __syncthreads();  // toks ready (iter 0) / LDS free (iter>0)
        // A: 64 tokens x 64 k fp32 -> bf16 hi/lo, fused sumsq
#pragma unroll
        for (int i = 0; i < 4; i++) {
            int id = tid + i * 256;
            int r = id >> 4, sg = id & 15;
            float4 v = *(const float4*)(x + (size_t)toks_s[r] * DIM + k0 + sg * 4);
            ps[i] = fmaf(v.x, v.x, fmaf(v.y, v.y, fmaf(v.z, v.z, fmaf(v.w, v.w, ps[i]))));
            ushort4 h, l;
            f2bf2(v.x, h.x, l.x); f2bf2(v.y, h.y, l.y);
            f2bf2(v.z, h.z, l.z); f2bf2(v.w, h.w, l.w);
            *(ushort4*)&Ah[r][sg * 4] = h;
            *(ushort4*)&Al[r][sg * 4] = l;
        }
        // B: 128 codes x 64 k bf16 planes -> LDS, XOR-swizzle 16B segs
#pragma unroll
        for (int i = 0; i < 4; i++) {
            int id = tid + i * 256;
            int r = id >> 3, p = id & 7;
            int dst = r * 64 + ((p ^ (r & 7)) << 3);
            *(short8*)&Bh[dst] = *(const short8*)(bh_slab + (size_t)r * DIM + k0 + p * 8);
            *(short8*)&Bl[dst] = *(const short8*)(bl_slab + (size_t)r * DIM + k0 + p * 8);
        }
        __syncthreads();
#pragma unroll
        for (int ks2 = 0; ks2 < 2; ks2++) {
            int ko = ks2 * 32 + q4 * 8;
            int g = ko >> 3;
            short8 ahf[2], alf[2], bhf[4], blf[4];
#pragma unroll
            for (int mi = 0; mi < 2; mi++) {
                int m = wm * 32 + mi * 16 + lc;
                ahf[mi] = *(const short8*)&Ah[m][ko];
                alf[mi] = *(const short8*)&Al[m][ko];
            }
#pragma unroll
            for (int ni = 0; ni < 4; ni++) {
                int n = wn * 64 + ni * 16 + lc;
                int bs = n * 64 + ((g ^ (lc & 7)) << 3);
                bhf[ni] = *(const short8*)&Bh[bs];
                blf[ni] = *(const short8*)&Bl[bs];
            }
#pragma unroll
            for (int mi = 0; mi < 2; mi++)
#pragma unroll
                for (int ni = 0; ni < 4; ni++) {
                    acc[mi][ni] = __builtin_amdgcn_mfma_f32_16x16x32_bf16(ahf[mi], bhf[ni], acc[mi][ni], 0, 0, 0);
                    acc[mi][ni] = __builtin_amdgcn_mfma_f32_16x16x32_bf16(ahf[mi], blf[ni], acc[mi][ni], 0, 0, 0);
                    acc[mi][ni] = __builtin_amdgcn_mfma_f32_16x16x32_bf16(alf[mi], bhf[ni], acc[mi][ni], 0, 0, 0);
                }
        }
    }

    // rnorm: reduce sumsq partials across 16-lane seg groups
#pragma unroll
    for (int m = 1; m <= 8; m <<= 1)
#pragma unroll
        for (int i = 0; i < 4; i++) ps[i] += __shfl_xor(ps[i], m);
    if ((lane & 15) == 0) {
#pragma unroll
        for (int i = 0; i < 4; i++) {
            int r = (tid >> 4) + 16 * i;
            rn_s[r] = 1.0f / fmaxf(sqrtf(ps[i]), 1e-12f);
        }
    }
    __syncthreads();

    // argmin: C/D layout col(lc)=code, row=(q4)*4+reg=token
#pragma unroll
    for (int mi = 0; mi < 2; mi++) {
#pragma unroll
        for (int r = 0; r < 4; r++) {
            int m = wm * 32 + mi * 16 + q4 * 4 + r;
            float rn2 = -2.0f * rn_s[m];
            float bv = 1e30f; int bc = 0;
#pragma unroll
            for (int ni = 0; ni < 4; ni++) {
                int n = wn * 64 + ni * 16 + lc;
                float d = fmaf(rn2, acc[mi][ni][r], sume_s[n]);
                if (d < bv) { bv = d; bc = n; }   // n ascending: strict < keeps lowest
            }
#pragma unroll
            for (int mk = 1; mk <= 8; mk <<= 1) {  // butterfly over 16-lane row group
                float ov = __shfl_xor(bv, mk);
                int oc = __shfl_xor(bc, mk);
                if (ov < bv || (ov == bv && oc < bc)) { bv = ov; bc = oc; }
            }
            if (lc == 0) { redv[m][wn] = bv; redi[m][wn] = bc; }
        }
    }
    __syncthreads();

    // final select per token (wave 0 only): idx + closed-form loss term 2 - 2*sim
    if (tid < 64) {
        float v0 = redv[tid][0], v1 = redv[tid][1];
        int c = (v1 < v0) ? redi[tid][1] : redi[tid][0];  // tie -> lower cols (wn=0)
        float bv = fminf(v0, v1);
        bestc[tid] = c;
        float term = 0.0f;
        if (tid < nt) {
            idxout[toks_s[tid]] = (float)(q * PT + c);
            term = 2.0f - (sume_s[c] - bv) * rinv_s[c];   // bv = sume_c - 2*rn*dot
        }
        for (int mk = 32; mk; mk >>= 1) term += __shfl_xor(term, mk);
        if (tid == 0) atomicAdd(&accg[0], term);
    }
    __syncthreads();

    // epilogue: out = quantized = emb[c]*rinv_c (== xn + (q - xn) numerically)
    for (int t = wv; t < nt; t += 4) {
        int c = bestc[t];
        int gt = toks_s[t];
        float rv = rinv_s[c];
        const float4* er = (const float4*)(emb + (size_t)(q * PT + c) * DIM);
        float4* orow = (float4*)(outbuf + (size_t)gt * DIM);
#pragma unroll
        for (int s2 = 0; s2 < 2; s2++) {
            float4 ev = er[lane * 2 + s2];
            orow[lane * 2 + s2] = make_float4(ev.x * rv, ev.y * rv, ev.z * rv, ev.w * rv);
        }
    }
}

// ---------------- uniform loss: block per row i, wave-per-j, 4-j batched reduction ----------------
__global__ __launch_bounds__(256) void k_uloss(const float* __restrict__ emb,
                                               const int* __restrict__ samp,
                                               const float* __restrict__ rinv,
                                               float* __restrict__ accg) {
    __shared__ float rs[4], rp[4];
    int i = blockIdx.x;
    int tid = threadIdx.x;
    int lane = tid & 63, wv = tid >> 6;
    int ci = samp[i];
    float rvi = rinv[ci];
    int labi = ci >> 7;
    const float4* ri = (const float4*)(emb + (size_t)ci * DIM);
    float4 e0 = ri[lane * 2], e1 = ri[lane * 2 + 1];   // row i in registers
    float sE = 0.0f, pE = 0.0f;
    for (int j0 = wv; j0 < NSAMP; j0 += 16) {
        float d[4]; int cj[4]; bool val[4];
#pragma unroll
        for (int u = 0; u < 4; u++) {
            int j = j0 + u * 4;
            val[u] = (j < NSAMP) && (j != i);
            int js = val[u] ? j : 0;
            cj[u] = samp[js];
            const float4* rj = (const float4*)(emb + (size_t)cj[u] * DIM);
            float4 f0 = rj[lane * 2], f1 = rj[lane * 2 + 1];
            d[u] = e0.x*f0.x + e0.y*f0.y + e0.z*f0.z + e0.w*f0.w
                 + e1.x*f1.x + e1.y*f1.y + e1.z*f1.z + e1.w*f1.w;
        }
#pragma unroll
        for (int mk = 32; mk; mk >>= 1)
#pragma unroll
            for (int u = 0; u < 4; u++) d[u] += __shfl_xor(d[u], mk);
#pragma unroll
        for (int u = 0; u < 4; u++) {
            float ex = val[u] ? expf(d[u] * rvi * rinv[cj[u]] * INV_TEMP) : 0.0f;
            sE += ex;
            if (val[u] && (cj[u] >> 7) == labi) pE += ex;
        }
    }
    if (lane == 0) { rs[wv] = sE; rp[wv] = pE; }
    __syncthreads();
    if (tid == 0) {
        float S = rs[0] + rs[1] + rs[2] + rs[3];
        float P = rp[0] + rp[1] + rp[2] + rp[3];
        atomicAdd(&accg[1], logf(S) - logf(P));
    }
}

// ---------------- finalize scalars ----------------
__global__ void k_final(const float* __restrict__ accg, float* __restrict__ lossp) {
    lossp[0] = 1.25f * accg[0] / (float)NTOK;   // loss terms already per-token means over dim
    lossp[1] = accg[1] / (float)NSAMP;
}

extern "C" void kernel_launch(void* const* d_in, const int* in_sizes, int n_in,
                              void* d_out, int out_size, void* d_ws, size_t ws_size,
                              hipStream_t stream) {
    const float* x   = (const float*)d_in[0];
    const float* emb = (const float*)d_in[1];
    const int* Q     = (const int*)d_in[2];
    const int* samp  = (const int*)d_in[3];

    float* out    = (float*)d_out;                       // [NTOK*DIM]
    float* lossp  = out + (size_t)NTOK * DIM;            // loss, uloss
    float* idxout = out + (size_t)NTOK * DIM + 2;        // [NTOK] idx as float

    unsigned short* Bhg = (unsigned short*)d_ws;         // NCODES*DIM bf16-hi
    unsigned short* Blg = Bhg + (size_t)NCODES * DIM;    // NCODES*DIM bf16-lo
    float* sume  = (float*)(Blg + (size_t)NCODES * DIM); // NCODES
    float* rinv  = sume + NCODES;                        // NCODES
    int* counts  = (int*)(rinv + NCODES);                // NTYPES
    int* offsg   = counts + NTYPES;                      // NTYPES+1
    int* rank    = offsg + NTYPES + 1;                   // NTOK
    int* order   = rank + NTOK;                          // NTOK
    float* accg  = (float*)(order + NTOK);               // [2]

    k_emb<<<NCODES / 4, 256, 0, stream>>>(emb, Bhg, Blg, sume, rinv, counts, accg);
    k_hist<<<NTOK / 256, 256, 0, stream>>>(Q, counts, rank);
    k_scatter<<<NTOK / 256, 256, 0, stream>>>(Q, counts, rank, order, offsg);
    dim3 gmain(NTYPES, MAXTILES);
    k_main<<<gmain, 256, 0, stream>>>(x, emb, Bhg, Blg, order, offsg, sume, rinv, out, idxout, accg);
    k_uloss<<<NSAMP, 256, 0, stream>>>(emb, samp, rinv, accg);
    k_final<<<1, 1, 0, stream>>>(accg, lossp);
}

// Round 4
// 213.914 us; speedup vs baseline: 2.9222x; 1.0051x over previous
//
#include <hip/hip_runtime.h>
#include <math.h>

#define NTOK   32768
#define DIM    512
#define NTYPES 26
#define PT     128
#define NCODES 3328
#define NSAMP  312
#define INV_TEMP (1.0f / 0.07f)
#define MAXTILES 24

typedef __attribute__((ext_vector_type(8))) short short8;
typedef __attribute__((ext_vector_type(4))) float floatx4;

// split f into bf16 hi + bf16 lo (RNE both), f ~= hi + lo to ~2^-17 rel
__device__ __forceinline__ void f2bf2(float f, unsigned short& h, unsigned short& l) {
    unsigned u = __float_as_uint(f);
    unsigned hb = (u + 0x7fffu + ((u >> 16) & 1u)) >> 16;
    h = (unsigned short)hb;
    float hf = __uint_as_float(hb << 16);
    float r = f - hf;
    unsigned u2 = __float_as_uint(r);
    l = (unsigned short)((u2 + 0x7fffu + ((u2 >> 16) & 1u)) >> 16);
}

// ---------------- emb precompute: bf16 hi/lo planes + sume + rinv; zero-init globals ----------------
__global__ __launch_bounds__(256) void k_emb(const float* __restrict__ emb,
                                             unsigned short* __restrict__ Bhg,
                                             unsigned short* __restrict__ Blg,
                                             float* __restrict__ sume,
                                             float* __restrict__ rinv,
                                             int* __restrict__ counts,
                                             float* __restrict__ accg) {
    int tid = threadIdx.x;
    if (blockIdx.x == 0) {
        if (tid < NTYPES) counts[tid] = 0;
        if (tid == 32) accg[0] = 0.0f;
        if (tid == 33) accg[1] = 0.0f;
    }
    int wv = tid >> 6, lane = tid & 63;
    int c = blockIdx.x * 4 + wv;
    const float4* row = (const float4*)(emb + (size_t)c * DIM);
    float4 v0 = row[lane * 2], v1 = row[lane * 2 + 1];
    float s = v0.x*v0.x + v0.y*v0.y + v0.z*v0.z + v0.w*v0.w
            + v1.x*v1.x + v1.y*v1.y + v1.z*v1.z + v1.w*v1.w;
    for (int m = 32; m; m >>= 1) s += __shfl_xor(s, m);
    if (lane == 0) {
        sume[c] = s;
        rinv[c] = 1.0f / fmaxf(sqrtf(s), 1e-12f);
    }
    union { short8 v; unsigned short u[8]; } hh, ll;
    f2bf2(v0.x, hh.u[0], ll.u[0]); f2bf2(v0.y, hh.u[1], ll.u[1]);
    f2bf2(v0.z, hh.u[2], ll.u[2]); f2bf2(v0.w, hh.u[3], ll.u[3]);
    f2bf2(v1.x, hh.u[4], ll.u[4]); f2bf2(v1.y, hh.u[5], ll.u[5]);
    f2bf2(v1.z, hh.u[6], ll.u[6]); f2bf2(v1.w, hh.u[7], ll.u[7]);
    *(short8*)(Bhg + (size_t)c * DIM + lane * 8) = hh.v;
    *(short8*)(Blg + (size_t)c * DIM + lane * 8) = ll.v;
}

// ---------------- two-level histogram: rank within type ----------------
__global__ __launch_bounds__(256) void k_hist(const int* __restrict__ Q,
                                              int* __restrict__ counts,
                                              int* __restrict__ rank) {
    __shared__ int lbin[NTYPES];
    __shared__ int lbase[NTYPES];
    int tid = threadIdx.x;
    if (tid < NTYPES) lbin[tid] = 0;
    __syncthreads();
    int t = blockIdx.x * 256 + tid;
    int qt = Q[t];
    int lr = atomicAdd(&lbin[qt], 1);
    __syncthreads();
    if (tid < NTYPES) lbase[tid] = atomicAdd(&counts[tid], lbin[tid]);
    __syncthreads();
    rank[t] = lbase[qt] + lr;
}

// ---------------- scatter (with in-block scan); block 0 publishes offs ----------------
__global__ __launch_bounds__(256) void k_scatter(const int* __restrict__ Q,
                                                 const int* __restrict__ counts,
                                                 const int* __restrict__ rank,
                                                 int* __restrict__ order,
                                                 int* __restrict__ offsg) {
    __shared__ int offs[NTYPES];
    int tid = threadIdx.x;
    if (tid == 0) {
        int a = 0;
        for (int i = 0; i < NTYPES; i++) {
            offs[i] = a;
            if (blockIdx.x == 0) offsg[i] = a;
            a += counts[i];
        }
        if (blockIdx.x == 0) offsg[NTYPES] = a;
    }
    __syncthreads();
    int t = blockIdx.x * 256 + tid;
    order[offs[Q[t]] + rank[t]] = t;
}

// ---------------- main: pipelined bf16x3 MFMA distance GEMM + argmin + epilogue ----------------
// block = 256 thr (4 waves). Tile: 64 tokens x 128 codes, K staged 64 at a time.
// Global loads for tile kc+1 are issued between the two barriers of tile kc, so the
// compiler's vmcnt(0)-before-barrier lands AFTER the ds_read+MFMA phase (latency hidden).
__global__ __launch_bounds__(256, 3) void k_main(const float* __restrict__ x,
                                                 const float* __restrict__ emb,
                                                 const unsigned short* __restrict__ Bhg,
                                                 const unsigned short* __restrict__ Blg,
                                                 const int* __restrict__ order,
                                                 const int* __restrict__ offsg,
                                                 const float* __restrict__ sume,
                                                 const float* __restrict__ rinv,
                                                 float* __restrict__ outbuf,
                                                 float* __restrict__ idxout,
                                                 float* __restrict__ accg) {
    int q = blockIdx.x;
    int tile = blockIdx.y;
    int base = offsg[q];
    int cnt = offsg[q + 1] - base;
    int tstart = tile * 64;
    if (tstart >= cnt) return;
    int nt = min(64, cnt - tstart);

    __shared__ unsigned short Ah[64][72];      // padded: 2-way-max banks
    __shared__ unsigned short Al[64][72];
    __shared__ unsigned short Bh[128 * 64];    // XOR-swizzled, unpadded
    __shared__ unsigned short Bl[128 * 64];
    __shared__ int   toks_s[64];
    __shared__ float rn_s[64];
    __shared__ float sume_s[128];
    __shared__ float rinv_s[128];
    __shared__ float redv[64][2];
    __shared__ int   redi[64][2];
    __shared__ int   bestc[64];

    int tid = threadIdx.x;
    int lane = tid & 63;
    int wv = tid >> 6;
    int wm = wv & 1, wn = wv >> 1;
    int lc = lane & 15;
    int q4 = lane >> 4;

    if (tid < 64) toks_s[tid] = order[base + tstart + min(tid, nt - 1)];
    if (tid < 128) {
        sume_s[tid] = sume[q * PT + tid];
        rinv_s[tid] = rinv[q * PT + tid];
    }

    // per-thread global pointers (A: 4 token rows; B: 4 code rows, hi+lo)
    const float* aptr[4];
    int arow = tid >> 4, asg = tid & 15;
#pragma unroll
    for (int i = 0; i < 4; i++) {
        int r = arow + 16 * i;
        int t = order[base + tstart + min(r, nt - 1)];   // direct read; L1/L2 broadcast
        aptr[i] = x + (size_t)t * DIM + asg * 4;
    }
    const unsigned short* bh_slab = Bhg + (size_t)q * PT * DIM;
    const unsigned short* bl_slab = Blg + (size_t)q * PT * DIM;
    size_t bofs[4];
#pragma unroll
    for (int i = 0; i < 4; i++) {
        int id = tid + i * 256;
        bofs[i] = (size_t)(id >> 3) * DIM + (id & 7) * 8;
    }

    floatx4 acc[2][4];
#pragma unroll
    for (int mi = 0; mi < 2; mi++)
#pragma unroll
        for (int ni = 0; ni < 4; ni++)
            acc[mi][ni] = (floatx4){0.f, 0.f, 0.f, 0.f};
    float ps[4] = {0.f, 0.f, 0.f, 0.f};   // sumsq partials, rows arow+16i

    // prologue prefetch (kc = 0)
    float4 va[4];
    short8 vbh[4], vbl[4];
#pragma unroll
    for (int i = 0; i < 4; i++) va[i] = *(const float4*)(aptr[i]);
#pragma unroll
    for (int i = 0; i < 4; i++) {
        vbh[i] = *(const short8*)(bh_slab + bofs[i]);
        vbl[i] = *(const short8*)(bl_slab + bofs[i]);
    }

    for (int kc = 0; kc < 8; kc++) {
        // convert + LDS stage (uses prefetched regs)
#pragma unroll
        for (int i = 0; i < 4; i++) {
            int r = arow + 16 * i;
            float4 v = va[i];
            ps[i] = fmaf(v.x, v.x, fmaf(v.y, v.y, fmaf(v.z, v.z, fmaf(v.w, v.w, ps[i]))));
            ushort4 h, l;
            f2bf2(v.x, h.x, l.x); f2bf2(v.y, h.y, l.y);
            f2bf2(v.z, h.z, l.z); f2bf2(v.w, h.w, l.w);
            *(ushort4*)&Ah[r][asg * 4] = h;
            *(ushort4*)&Al[r][asg * 4] = l;
        }
#pragma unroll
        for (int i = 0; i < 4; i++) {
            int id = tid + i * 256;
            int r = id >> 3, p = id & 7;
            int dst = r * 64 + ((p ^ (r & 7)) << 3);
            *(short8*)&Bh[dst] = vbh[i];
            *(short8*)&Bl[dst] = vbl[i];
        }
        __syncthreads();   // tile kc staged
        // prefetch tile kc+1 — flies during the MFMA phase below
        if (kc < 7) {
            int k0n = (kc + 1) * 64;
#pragma unroll
            for (int i = 0; i < 4; i++) va[i] = *(const float4*)(aptr[i] + k0n);
#pragma unroll
            for (int i = 0; i < 4; i++) {
                vbh[i] = *(const short8*)(bh_slab + bofs[i] + k0n);
                vbl[i] = *(const short8*)(bl_slab + bofs[i] + k0n);
            }
        }
        // compute on tile kc
#pragma unroll
        for (int ks2 = 0; ks2 < 2; ks2++) {
            int ko = ks2 * 32 + q4 * 8;
            int g = ko >> 3;
            short8 ahf[2], alf[2], bhf[4], blf[4];
#pragma unroll
            for (int mi = 0; mi < 2; mi++) {
                int m = wm * 32 + mi * 16 + lc;
                ahf[mi] = *(const short8*)&Ah[m][ko];
                alf[mi] = *(const short8*)&Al[m][ko];
            }
#pragma unroll
            for (int ni = 0; ni < 4; ni++) {
                int n = wn * 64 + ni * 16 + lc;
                int bs = n * 64 + ((g ^ (lc & 7)) << 3);
                bhf[ni] = *(const short8*)&Bh[bs];
                blf[ni] = *(const short8*)&Bl[bs];
            }
#pragma unroll
            for (int mi = 0; mi < 2; mi++)
#pragma unroll
                for (int ni = 0; ni < 4; ni++) {
                    acc[mi][ni] = __builtin_amdgcn_mfma_f32_16x16x32_bf16(ahf[mi], bhf[ni], acc[mi][ni], 0, 0, 0);
                    acc[mi][ni] = __builtin_amdgcn_mfma_f32_16x16x32_bf16(ahf[mi], blf[ni], acc[mi][ni], 0, 0, 0);
                    acc[mi][ni] = __builtin_amdgcn_mfma_f32_16x16x32_bf16(alf[mi], bhf[ni], acc[mi][ni], 0, 0, 0);
                }
        }
        __syncthreads();   // tile kc consumed (drains prefetch vmcnt too — intended)
    }

    // rnorm: reduce sumsq partials across 16-lane seg groups
#pragma unroll
    for (int m = 1; m <= 8; m <<= 1)
#pragma unroll
        for (int i = 0; i < 4; i++) ps[i] += __shfl_xor(ps[i], m);
    if ((lane & 15) == 0) {
#pragma unroll
        for (int i = 0; i < 4; i++)
            rn_s[arow + 16 * i] = 1.0f / fmaxf(sqrtf(ps[i]), 1e-12f);
    }
    __syncthreads();

    // argmin: C/D layout col(lc)=code, row=q4*4+reg=token
#pragma unroll
    for (int mi = 0; mi < 2; mi++) {
#pragma unroll
        for (int r = 0; r < 4; r++) {
            int m = wm * 32 + mi * 16 + q4 * 4 + r;
            float rn2 = -2.0f * rn_s[m];
            float bv = 1e30f; int bc = 0;
#pragma unroll
            for (int ni = 0; ni < 4; ni++) {
                int n = wn * 64 + ni * 16 + lc;
                float d = fmaf(rn2, acc[mi][ni][r], sume_s[n]);
                if (d < bv) { bv = d; bc = n; }   // n ascending: strict < keeps lowest
            }
#pragma unroll
            for (int mk = 1; mk <= 8; mk <<= 1) {
                float ov = __shfl_xor(bv, mk);
                int oc = __shfl_xor(bc, mk);
                if (ov < bv || (ov == bv && oc < bc)) { bv = ov; bc = oc; }
            }
            if (lc == 0) { redv[m][wn] = bv; redi[m][wn] = bc; }
        }
    }
    __syncthreads();

    // final select per token: idx + closed-form loss row-sum 2 - 2*sim
    if (tid < 64) {
        float v0 = redv[tid][0], v1 = redv[tid][1];
        int c = (v1 < v0) ? redi[tid][1] : redi[tid][0];  // tie -> lower cols
        float bv = fminf(v0, v1);
        bestc[tid] = c;
        float term = 0.0f;
        if (tid < nt) {
            idxout[toks_s[tid]] = (float)(q * PT + c);
            term = 2.0f - (sume_s[c] - bv) * rinv_s[c];   // bv = sume_c - 2*rn*dot
        }
        for (int mk = 32; mk; mk >>= 1) term += __shfl_xor(term, mk);
        if (tid == 0) atomicAdd(&accg[0], term);
    }
    __syncthreads();

    // epilogue: out = quantized = emb[c]*rinv_c (== xn + (q - xn) numerically)
    for (int t = wv; t < nt; t += 4) {
        int c = bestc[t];
        int gt = toks_s[t];
        float rv = rinv_s[c];
        const float4* er = (const float4*)(emb + (size_t)(q * PT + c) * DIM);
        float4* orow = (float4*)(outbuf + (size_t)gt * DIM);
#pragma unroll
        for (int s2 = 0; s2 < 2; s2++) {
            float4 ev = er[lane * 2 + s2];
            orow[lane * 2 + s2] = make_float4(ev.x * rv, ev.y * rv, ev.z * rv, ev.w * rv);
        }
    }
}

// ---------------- uniform loss: block per row i, wave-per-j, 4-j batched ----------------
__global__ __launch_bounds__(256) void k_uloss(const float* __restrict__ emb,
                                               const int* __restrict__ samp,
                                               const float* __restrict__ rinv,
                                               float* __restrict__ accg) {
    __shared__ float rs[4], rp[4];
    int i = blockIdx.x;
    int tid = threadIdx.x;
    int lane = tid & 63, wv = tid >> 6;
    int ci = samp[i];
    float rvi = rinv[ci];
    int labi = ci >> 7;
    const float4* ri = (const float4*)(emb + (size_t)ci * DIM);
    float4 e0 = ri[lane * 2], e1 = ri[lane * 2 + 1];
    float sE = 0.0f, pE = 0.0f;
    for (int j0 = wv; j0 < NSAMP; j0 += 16) {
        float d[4]; int cj[4]; bool val[4];
#pragma unroll
        for (int u = 0; u < 4; u++) {
            int j = j0 + u * 4;
            val[u] = (j < NSAMP) && (j != i);
            int js = val[u] ? j : 0;
            cj[u] = samp[js];
            const float4* rj = (const float4*)(emb + (size_t)cj[u] * DIM);
            float4 f0 = rj[lane * 2], f1 = rj[lane * 2 + 1];
            d[u] = e0.x*f0.x + e0.y*f0.y + e0.z*f0.z + e0.w*f0.w
                 + e1.x*f1.x + e1.y*f1.y + e1.z*f1.z + e1.w*f1.w;
        }
#pragma unroll
        for (int mk = 32; mk; mk >>= 1)
#pragma unroll
            for (int u = 0; u < 4; u++) d[u] += __shfl_xor(d[u], mk);
#pragma unroll
        for (int u = 0; u < 4; u++) {
            float ex = val[u] ? expf(d[u] * rvi * rinv[cj[u]] * INV_TEMP) : 0.0f;
            sE += ex;
            if (val[u] && (cj[u] >> 7) == labi) pE += ex;
        }
    }
    if (lane == 0) { rs[wv] = sE; rp[wv] = pE; }
    __syncthreads();
    if (tid == 0) {
        float S = rs[0] + rs[1] + rs[2] + rs[3];
        float P = rp[0] + rp[1] + rp[2] + rp[3];
        atomicAdd(&accg[1], logf(S) - logf(P));
    }
}

// ---------------- finalize scalars ----------------
__global__ void k_final(const float* __restrict__ accg, float* __restrict__ lossp) {
    // accg[0] = sum over tokens of ||q - xn||^2 (row sums); reference mean is over NTOK*DIM
    lossp[0] = (1.25f / ((float)NTOK * (float)DIM)) * accg[0];
    lossp[1] = accg[1] / (float)NSAMP;
}

extern "C" void kernel_launch(void* const* d_in, const int* in_sizes, int n_in,
                              void* d_out, int out_size, void* d_ws, size_t ws_size,
                              hipStream_t stream) {
    const float* x   = (const float*)d_in[0];
    const float* emb = (const float*)d_in[1];
    const int* Q     = (const int*)d_in[2];
    const int* samp  = (const int*)d_in[3];

    float* out    = (float*)d_out;                       // [NTOK*DIM]
    float* lossp  = out + (size_t)NTOK * DIM;            // loss, uloss
    float* idxout = out + (size_t)NTOK * DIM + 2;        // [NTOK] idx as float

    unsigned short* Bhg = (unsigned short*)d_ws;         // NCODES*DIM bf16-hi
    unsigned short* Blg = Bhg + (size_t)NCODES * DIM;    // NCODES*DIM bf16-lo
    float* sume  = (float*)(Blg + (size_t)NCODES * DIM); // NCODES
    float* rinv  = sume + NCODES;                        // NCODES
    int* counts  = (int*)(rinv + NCODES);                // NTYPES
    int* offsg   = counts + NTYPES;                      // NTYPES+1
    int* rank    = offsg + NTYPES + 1;                   // NTOK
    int* order   = rank + NTOK;                          // NTOK
    float* accg  = (float*)(order + NTOK);               // [2]

    k_emb<<<NCODES / 4, 256, 0, stream>>>(emb, Bhg, Blg, sume, rinv, counts, accg);
    k_hist<<<NTOK / 256, 256, 0, stream>>>(Q, counts, rank);
    k_scatter<<<NTOK / 256, 256, 0, stream>>>(Q, counts, rank, order, offsg);
    dim3 gmain(NTYPES, MAXTILES);
    k_main<<<gmain, 256, 0, stream>>>(x, emb, Bhg, Blg, order, offsg, sume, rinv, out, idxout, accg);
    k_uloss<<<NSAMP, 256, 0, stream>>>(emb, samp, rinv, accg);
    k_final<<<1, 1, 0, stream>>>(accg, lossp);
}